// Round 1
// baseline (1874.441 us; speedup 1.0000x reference)
//
#include <hip/hip_runtime.h>
#include <math.h>

// GCN 5-layer on MI355X.
// Strategy:
//  - gcn_norm: deg via atomics (weighted) + edge counts, dinv = rsqrt(deg+1)
//  - build CSC (edges sorted by target col) once per call: hist -> scan -> scatter
//  - layer 1: aggregate vertex_features (D=6) FIRST, then dense 6->64 (+bias+sigmoid)
//      valid because A@(x@W) == (A@x)@W
//  - layers 2-4: tiled f32 GEMM 64x64, then gather-based aggregation (wave per node,
//      lane = feature, self-loop = dinv^2 * h[node])
//  - layer 5: dot with W5 (N x 1) first, then scalar aggregation + sigmoid + mean

__device__ __forceinline__ float sigf(float x) { return 1.0f / (1.0f + expf(-x)); }

__global__ __launch_bounds__(256) void k_hist(const int* __restrict__ col,
                                              const float* __restrict__ w,
                                              float* __restrict__ degf,
                                              int* __restrict__ cnt, int E) {
  int e = blockIdx.x * 256 + threadIdx.x;
  if (e < E) {
    int c = col[e];
    atomicAdd(&degf[c], w[e]);
    atomicAdd(&cnt[c], 1);
  }
}

__global__ __launch_bounds__(256) void k_dinv(float* __restrict__ d, int N) {
  int i = blockIdx.x * 256 + threadIdx.x;
  if (i < N) d[i] = rsqrtf(d[i] + 1.0f);  // +1.0 = self-loop weight; always > 0
}

__global__ __launch_bounds__(1024) void k_scan(const int* __restrict__ cnt,
                                               int* __restrict__ off,
                                               int* __restrict__ next, int N) {
  __shared__ int lds[1024];
  int t = threadIdx.x;
  int chunk = (N + 1023) / 1024;
  int lo = t * chunk; if (lo > N) lo = N;
  int hi = lo + chunk; if (hi > N) hi = N;
  int s = 0;
  for (int i = lo; i < hi; ++i) s += cnt[i];
  lds[t] = s;
  __syncthreads();
  for (int d = 1; d < 1024; d <<= 1) {
    int v = (t >= d) ? lds[t - d] : 0;
    __syncthreads();
    lds[t] += v;
    __syncthreads();
  }
  int run = lds[t] - s;  // exclusive prefix
  for (int i = lo; i < hi; ++i) {
    off[i] = run;
    next[i] = run;
    run += cnt[i];
  }
  if (t == 1023) off[N] = lds[1023];
}

__global__ __launch_bounds__(256) void k_scatter(const int* __restrict__ row,
                                                 const int* __restrict__ col,
                                                 const float* __restrict__ w,
                                                 const float* __restrict__ dinv,
                                                 int* __restrict__ next,
                                                 int* __restrict__ srow,
                                                 float* __restrict__ snorm, int E) {
  int e = blockIdx.x * 256 + threadIdx.x;
  if (e < E) {
    int c = col[e], r = row[e];
    int pos = atomicAdd(&next[c], 1);
    srow[pos] = r;
    snorm[pos] = dinv[r] * w[e] * dinv[c];
  }
}

// Aggregate vertex features (D=6). 8 lanes per node, lane%8 = feature.
__global__ __launch_bounds__(256) void k_agg6(const float* __restrict__ vf,
                                              const float* __restrict__ dinv,
                                              const int* __restrict__ off,
                                              const int* __restrict__ srow,
                                              const float* __restrict__ snorm,
                                              float* __restrict__ Sx, int N) {
  int t = threadIdx.x;
  int g = t >> 3, f = t & 7;
  int node = blockIdx.x * 32 + g;
  if (node >= N) return;
  bool act = f < 6;
  float di = dinv[node];
  float acc = act ? di * di * vf[node * 6 + f] : 0.0f;
  int e1 = off[node + 1];
  for (int e = off[node]; e < e1; ++e) {
    int r = srow[e];
    float nm = snorm[e];
    if (act) acc += nm * vf[r * 6 + f];
  }
  if (act) Sx[node * 6 + f] = acc;
}

// X = sigmoid(Sx @ W1 + b1), Sx [N,6], W1 [6,64]
__global__ __launch_bounds__(256) void k_gemm1(const float* __restrict__ Sx,
                                               const float* __restrict__ W1,
                                               const float* __restrict__ b1,
                                               float* __restrict__ X, int N) {
  __shared__ float Wl[6 * 64];
  __shared__ float bl[64];
  __shared__ float XT[6 * 65];
  int t = threadIdx.x;
  int n0 = blockIdx.x * 64;
  for (int i = t; i < 384; i += 256) {
    Wl[i] = W1[i];
    int n = i / 6, k = i - n * 6;
    int node = n0 + n;
    XT[k * 65 + n] = (node < N) ? Sx[node * 6 + k] : 0.0f;
  }
  if (t < 64) bl[t] = b1[t];
  __syncthreads();
  int c0 = (t & 15) * 4;
  int nn = (t >> 4) * 4;
  float acc[4][4];
#pragma unroll
  for (int i = 0; i < 4; ++i)
#pragma unroll
    for (int j = 0; j < 4; ++j) acc[i][j] = bl[c0 + j];
#pragma unroll
  for (int k = 0; k < 6; ++k) {
    float4 wv = *(const float4*)&Wl[k * 64 + c0];
    float xv[4];
#pragma unroll
    for (int i = 0; i < 4; ++i) xv[i] = XT[k * 65 + nn + i];
#pragma unroll
    for (int i = 0; i < 4; ++i) {
      acc[i][0] += xv[i] * wv.x;
      acc[i][1] += xv[i] * wv.y;
      acc[i][2] += xv[i] * wv.z;
      acc[i][3] += xv[i] * wv.w;
    }
  }
#pragma unroll
  for (int i = 0; i < 4; ++i) {
    int node = n0 + nn + i;
    if (node < N) {
      float4 o;
      o.x = sigf(acc[i][0]); o.y = sigf(acc[i][1]);
      o.z = sigf(acc[i][2]); o.w = sigf(acc[i][3]);
      *(float4*)&X[node * 64 + c0] = o;
    }
  }
}

// H = X @ W  (X [N,64], W [64,64] row-major). 64x64 tile per block.
__global__ __launch_bounds__(256) void k_gemm64(const float* __restrict__ Xin,
                                                const float* __restrict__ W,
                                                float* __restrict__ Hout, int N) {
  __shared__ float XT[64 * 65];  // [k][n], padded
  __shared__ float Wl[64 * 64];  // [k][c]
  int t = threadIdx.x;
  int n0 = blockIdx.x * 64;
#pragma unroll
  for (int i = 0; i < 4; ++i) {
    int idx = (i * 256 + t) * 4;
    *(float4*)&Wl[idx] = *(const float4*)&W[idx];
  }
#pragma unroll
  for (int i = 0; i < 4; ++i) {
    int idx = (i * 256 + t) * 4;
    int n = idx >> 6, k = idx & 63;
    int node = n0 + n;
    float4 xv = make_float4(0.f, 0.f, 0.f, 0.f);
    if (node < N) xv = *(const float4*)&Xin[node * 64 + k];
    XT[k * 65 + n] = xv.x;
    XT[(k + 1) * 65 + n] = xv.y;
    XT[(k + 2) * 65 + n] = xv.z;
    XT[(k + 3) * 65 + n] = xv.w;
  }
  __syncthreads();
  int c0 = (t & 15) * 4;
  int nn = (t >> 4) * 4;
  float acc[4][4] = {{0.f}};
#pragma unroll
  for (int k = 0; k < 64; ++k) {
    float4 wv = *(const float4*)&Wl[k * 64 + c0];
    float xv[4];
#pragma unroll
    for (int i = 0; i < 4; ++i) xv[i] = XT[k * 65 + nn + i];
#pragma unroll
    for (int i = 0; i < 4; ++i) {
      acc[i][0] += xv[i] * wv.x;
      acc[i][1] += xv[i] * wv.y;
      acc[i][2] += xv[i] * wv.z;
      acc[i][3] += xv[i] * wv.w;
    }
  }
#pragma unroll
  for (int i = 0; i < 4; ++i) {
    int node = n0 + nn + i;
    if (node < N) {
      float4 o = make_float4(acc[i][0], acc[i][1], acc[i][2], acc[i][3]);
      *(float4*)&Hout[node * 64 + c0] = o;
    }
  }
}

// Xout = sigmoid(A_norm . Hin + b). One wave per node, lane = feature.
__global__ __launch_bounds__(256) void k_agg64(const float* __restrict__ Hin,
                                               const float* __restrict__ dinv,
                                               const int* __restrict__ off,
                                               const int* __restrict__ srow,
                                               const float* __restrict__ snorm,
                                               const float* __restrict__ b,
                                               float* __restrict__ Xout, int N) {
  int lane = threadIdx.x & 63;
  int wid = threadIdx.x >> 6;
  int node = blockIdx.x * 4 + wid;
  if (node >= N) return;
  float di = dinv[node];
  float acc = di * di * Hin[node * 64 + lane];  // self-loop
  int e1 = off[node + 1];
  // e, srow[e], snorm[e] are wave-uniform -> scalar loads; gather is 256B coalesced
  for (int e = off[node]; e < e1; ++e) {
    int r = srow[e];
    float nm = snorm[e];
    acc += nm * Hin[r * 64 + lane];
  }
  Xout[node * 64 + lane] = sigf(acc + b[lane]);
}

// h5[n] = dot(X[n,:], W5[:,0])
__global__ __launch_bounds__(256) void k_dot5(const float* __restrict__ Xin,
                                              const float* __restrict__ W5,
                                              float* __restrict__ h5, int N) {
  int lane = threadIdx.x & 63;
  int wid = threadIdx.x >> 6;
  int node = blockIdx.x * 4 + wid;
  if (node >= N) return;
  float v = Xin[node * 64 + lane] * W5[lane];
#pragma unroll
  for (int d = 32; d; d >>= 1) v += __shfl_xor(v, d);
  if (lane == 0) h5[node] = v;
}

// scalar aggregation + sigmoid + per-block partial sum
__global__ __launch_bounds__(256) void k_agg5(const float* __restrict__ h5,
                                              const float* __restrict__ dinv,
                                              const int* __restrict__ off,
                                              const int* __restrict__ srow,
                                              const float* __restrict__ snorm,
                                              const float* __restrict__ b5,
                                              float* __restrict__ partials, int N) {
  int n = blockIdx.x * 256 + threadIdx.x;
  float sig = 0.0f;
  if (n < N) {
    float di = dinv[n];
    float acc = di * di * h5[n];
    int e1 = off[n + 1];
    for (int e = off[n]; e < e1; ++e) acc += snorm[e] * h5[srow[e]];
    sig = sigf(acc + b5[0]);
  }
#pragma unroll
  for (int d = 32; d; d >>= 1) sig += __shfl_xor(sig, d);
  __shared__ float ws[4];
  int lane = threadIdx.x & 63, wid = threadIdx.x >> 6;
  if (lane == 0) ws[wid] = sig;
  __syncthreads();
  if (threadIdx.x == 0) partials[blockIdx.x] = ws[0] + ws[1] + ws[2] + ws[3];
}

__global__ __launch_bounds__(512) void k_final(const float* __restrict__ partials,
                                               float* __restrict__ out, int nb,
                                               float invN) {
  float v = 0.0f;
  for (int i = threadIdx.x; i < nb; i += 512) v += partials[i];
#pragma unroll
  for (int d = 32; d; d >>= 1) v += __shfl_xor(v, d);
  __shared__ float ws[8];
  int lane = threadIdx.x & 63, wid = threadIdx.x >> 6;
  if (lane == 0) ws[wid] = v;
  __syncthreads();
  if (threadIdx.x == 0) {
    float s = 0.0f;
    for (int i = 0; i < 8; ++i) s += ws[i];
    out[0] = s * invN;
  }
}

extern "C" void kernel_launch(void* const* d_in, const int* in_sizes, int n_in,
                              void* d_out, int out_size, void* d_ws, size_t ws_size,
                              hipStream_t stream) {
  const float* vf = (const float*)d_in[0];
  const int* edges = (const int*)d_in[1];
  const float* w = (const float*)d_in[2];
  const float* W1 = (const float*)d_in[3];
  const float* b1 = (const float*)d_in[4];
  const float* W2 = (const float*)d_in[5];
  const float* b2 = (const float*)d_in[6];
  const float* W3 = (const float*)d_in[7];
  const float* b3 = (const float*)d_in[8];
  const float* W4 = (const float*)d_in[9];
  const float* b4 = (const float*)d_in[10];
  const float* W5 = (const float*)d_in[11];
  const float* b5 = (const float*)d_in[12];
  float* out = (float*)d_out;

  const int N = in_sizes[0] / 6;
  const int E = in_sizes[2];
  const int* row = edges;
  const int* col = edges + E;

  // workspace carve-up
  size_t o = 0;
  auto carve = [&](size_t bytes) -> void* {
    void* p = (char*)d_ws + o;
    o += (bytes + 255) & ~(size_t)255;
    return p;
  };
  float* X = (float*)carve((size_t)N * 64 * 4);
  float* H = (float*)carve((size_t)N * 64 * 4);  // also holds Sx [N,6]
  int* srow = (int*)carve((size_t)E * 4);
  float* snorm = (float*)carve((size_t)E * 4);
  float* dinv = (float*)carve((size_t)N * 4);
  int* off = (int*)carve((size_t)(N + 1) * 4);
  int* next = (int*)carve((size_t)N * 4);
  int* cnt = (int*)carve((size_t)N * 4);
  float* h5 = (float*)carve((size_t)N * 4);
  const int nb5 = (N + 255) / 256;
  float* partials = (float*)carve((size_t)nb5 * 4);

  hipMemsetAsync(dinv, 0, (size_t)N * 4, stream);
  hipMemsetAsync(cnt, 0, (size_t)N * 4, stream);

  const int eb = (E + 255) / 256;
  k_hist<<<eb, 256, 0, stream>>>(col, w, dinv, cnt, E);
  k_dinv<<<(N + 255) / 256, 256, 0, stream>>>(dinv, N);
  k_scan<<<1, 1024, 0, stream>>>(cnt, off, next, N);
  k_scatter<<<eb, 256, 0, stream>>>(row, col, w, dinv, next, srow, snorm, E);

  // layer 1: aggregate features (D=6) then dense 6->64
  k_agg6<<<(N + 31) / 32, 256, 0, stream>>>(vf, dinv, off, srow, snorm, H, N);
  k_gemm1<<<(N + 63) / 64, 256, 0, stream>>>(H, W1, b1, X, N);

  // layers 2-4
  const float* Ws[3] = {W2, W3, W4};
  const float* bs[3] = {b2, b3, b4};
  for (int l = 0; l < 3; ++l) {
    k_gemm64<<<(N + 63) / 64, 256, 0, stream>>>(X, Ws[l], H, N);
    k_agg64<<<(N + 3) / 4, 256, 0, stream>>>(H, dinv, off, srow, snorm, bs[l], X, N);
  }

  // layer 5: dot first (dout=1), then scalar aggregation + mean
  k_dot5<<<(N + 3) / 4, 256, 0, stream>>>(X, W5, h5, N);
  k_agg5<<<nb5, 256, 0, stream>>>(h5, dinv, off, srow, snorm, b5, partials, N);
  k_final<<<1, 512, 0, stream>>>(partials, out, nb5, 1.0f / (float)N);
}

// Round 3
// 1430.381 us; speedup vs baseline: 1.3104x; 1.3104x over previous
//
#include <hip/hip_runtime.h>
#include <math.h>

// GCN 5-layer on MI355X — round 2 (resubmit after infra failure).
// CSC build with minimized atomic traffic:
//   k_hist: 1 int atomic per edge (count only)
//   k_scan: offsets
//   k_scatter: 1 atomic + ONE int2 {row, w} 8B store per edge (interleaved)
//   k_deg:  weighted degree from SORTED weights (coalesced, no atomics) -> dinv
//   k_norm: edat.y <- dinv[row]*w*dinv[col] in place (dinv is L2-resident)
// Layers:
//   L1: aggregate 6-wide first (A@(xW) == (A@x)@W), then 6->64 dense
//   L2-4: tiled f32 GEMM 64x64 + wave-per-node gather aggregation
//   L4 agg fused with the W5 dot (dout=1) -> h5; L5 = scalar agg + mean

__device__ __forceinline__ float sigf(float x) { return 1.0f / (1.0f + expf(-x)); }

__global__ __launch_bounds__(256) void k_hist(const int* __restrict__ col,
                                              int* __restrict__ cnt, int E) {
  int e = blockIdx.x * 256 + threadIdx.x;
  if (e < E) atomicAdd(&cnt[col[e]], 1);
}

__global__ __launch_bounds__(1024) void k_scan(const int* __restrict__ cnt,
                                               int* __restrict__ off,
                                               int* __restrict__ next, int N) {
  __shared__ int lds[1024];
  int t = threadIdx.x;
  int chunk = (N + 1023) / 1024;
  int lo = t * chunk; if (lo > N) lo = N;
  int hi = lo + chunk; if (hi > N) hi = N;
  int s = 0;
  for (int i = lo; i < hi; ++i) s += cnt[i];
  lds[t] = s;
  __syncthreads();
  for (int d = 1; d < 1024; d <<= 1) {
    int v = (t >= d) ? lds[t - d] : 0;
    __syncthreads();
    lds[t] += v;
    __syncthreads();
  }
  int run = lds[t] - s;  // exclusive prefix
  for (int i = lo; i < hi; ++i) {
    off[i] = run;
    next[i] = run;
    run += cnt[i];
  }
  if (t == 1023) off[N] = lds[1023];
}

__global__ __launch_bounds__(256) void k_scatter(const int* __restrict__ row,
                                                 const int* __restrict__ col,
                                                 const float* __restrict__ w,
                                                 int* __restrict__ next,
                                                 int2* __restrict__ edat, int E) {
  int e = blockIdx.x * 256 + threadIdx.x;
  if (e < E) {
    int c = col[e];
    int pos = atomicAdd(&next[c], 1);
    edat[pos] = make_int2(row[e], __float_as_int(w[e]));
  }
}

// dinv[n] = rsqrt(sum_w(in-edges) + 1)   from sorted weights, wave per node
__global__ __launch_bounds__(256) void k_deg(const int2* __restrict__ edat,
                                             const int* __restrict__ off,
                                             float* __restrict__ dinv, int N) {
  int lane = threadIdx.x & 63, wid = threadIdx.x >> 6;
  int node = blockIdx.x * 4 + wid;
  if (node >= N) return;
  int e0 = off[node], e1 = off[node + 1];
  float s = 0.0f;
  for (int e = e0 + lane; e < e1; e += 64) s += __int_as_float(edat[e].y);
#pragma unroll
  for (int d = 32; d; d >>= 1) s += __shfl_xor(s, d);
  if (lane == 0) dinv[node] = rsqrtf(s + 1.0f);
}

// edat.y <- dinv[row]*w*dinv[col]  (in place)
__global__ __launch_bounds__(256) void k_norm(int2* __restrict__ edat,
                                              const int* __restrict__ off,
                                              const float* __restrict__ dinv, int N) {
  int lane = threadIdx.x & 63, wid = threadIdx.x >> 6;
  int node = blockIdx.x * 4 + wid;
  if (node >= N) return;
  float dc = dinv[node];
  int e0 = off[node], e1 = off[node + 1];
  for (int e = e0 + lane; e < e1; e += 64) {
    int2 a = edat[e];
    edat[e].y = __float_as_int(dinv[a.x] * __int_as_float(a.y) * dc);
  }
}

// Aggregate vertex features (D=6). 8 lanes per node, lane&7 = feature.
__global__ __launch_bounds__(256) void k_agg6(const float* __restrict__ vf,
                                              const float* __restrict__ dinv,
                                              const int* __restrict__ off,
                                              const int2* __restrict__ edat,
                                              float* __restrict__ Sx, int N) {
  int t = threadIdx.x;
  int g = t >> 3, f = t & 7;
  int node = blockIdx.x * 32 + g;
  if (node >= N) return;
  bool act = f < 6;
  float di = dinv[node];
  float acc = act ? di * di * vf[node * 6 + f] : 0.0f;
  int e1 = off[node + 1];
  for (int e = off[node]; e < e1; ++e) {
    int2 a = edat[e];
    if (act) acc += __int_as_float(a.y) * vf[a.x * 6 + f];
  }
  if (act) Sx[node * 6 + f] = acc;
}

// X = sigmoid(Sx @ W1 + b1), Sx [N,6], W1 [6,64]
__global__ __launch_bounds__(256) void k_gemm1(const float* __restrict__ Sx,
                                               const float* __restrict__ W1,
                                               const float* __restrict__ b1,
                                               float* __restrict__ X, int N) {
  __shared__ float Wl[6 * 64];
  __shared__ float bl[64];
  __shared__ float XT[6 * 65];
  int t = threadIdx.x;
  int n0 = blockIdx.x * 64;
  for (int i = t; i < 384; i += 256) {
    Wl[i] = W1[i];
    int n = i / 6, k = i - n * 6;
    int node = n0 + n;
    XT[k * 65 + n] = (node < N) ? Sx[node * 6 + k] : 0.0f;
  }
  if (t < 64) bl[t] = b1[t];
  __syncthreads();
  int c0 = (t & 15) * 4;
  int nn = (t >> 4) * 4;
  float acc[4][4];
#pragma unroll
  for (int i = 0; i < 4; ++i)
#pragma unroll
    for (int j = 0; j < 4; ++j) acc[i][j] = bl[c0 + j];
#pragma unroll
  for (int k = 0; k < 6; ++k) {
    float4 wv = *(const float4*)&Wl[k * 64 + c0];
    float xv[4];
#pragma unroll
    for (int i = 0; i < 4; ++i) xv[i] = XT[k * 65 + nn + i];
#pragma unroll
    for (int i = 0; i < 4; ++i) {
      acc[i][0] += xv[i] * wv.x;
      acc[i][1] += xv[i] * wv.y;
      acc[i][2] += xv[i] * wv.z;
      acc[i][3] += xv[i] * wv.w;
    }
  }
#pragma unroll
  for (int i = 0; i < 4; ++i) {
    int node = n0 + nn + i;
    if (node < N) {
      float4 o;
      o.x = sigf(acc[i][0]); o.y = sigf(acc[i][1]);
      o.z = sigf(acc[i][2]); o.w = sigf(acc[i][3]);
      *(float4*)&X[node * 64 + c0] = o;
    }
  }
}

// H = X @ W  (X [N,64], W [64,64] row-major). 64x64 tile per block.
__global__ __launch_bounds__(256) void k_gemm64(const float* __restrict__ Xin,
                                                const float* __restrict__ W,
                                                float* __restrict__ Hout, int N) {
  __shared__ float XT[64 * 65];  // [k][n], padded
  __shared__ float Wl[64 * 64];  // [k][c]
  int t = threadIdx.x;
  int n0 = blockIdx.x * 64;
#pragma unroll
  for (int i = 0; i < 4; ++i) {
    int idx = (i * 256 + t) * 4;
    *(float4*)&Wl[idx] = *(const float4*)&W[idx];
  }
#pragma unroll
  for (int i = 0; i < 4; ++i) {
    int idx = (i * 256 + t) * 4;
    int n = idx >> 6, k = idx & 63;
    int node = n0 + n;
    float4 xv = make_float4(0.f, 0.f, 0.f, 0.f);
    if (node < N) xv = *(const float4*)&Xin[node * 64 + k];
    XT[k * 65 + n] = xv.x;
    XT[(k + 1) * 65 + n] = xv.y;
    XT[(k + 2) * 65 + n] = xv.z;
    XT[(k + 3) * 65 + n] = xv.w;
  }
  __syncthreads();
  int c0 = (t & 15) * 4;
  int nn = (t >> 4) * 4;
  float acc[4][4] = {{0.f}};
#pragma unroll
  for (int k = 0; k < 64; ++k) {
    float4 wv = *(const float4*)&Wl[k * 64 + c0];
    float xv[4];
#pragma unroll
    for (int i = 0; i < 4; ++i) xv[i] = XT[k * 65 + nn + i];
#pragma unroll
    for (int i = 0; i < 4; ++i) {
      acc[i][0] += xv[i] * wv.x;
      acc[i][1] += xv[i] * wv.y;
      acc[i][2] += xv[i] * wv.z;
      acc[i][3] += xv[i] * wv.w;
    }
  }
#pragma unroll
  for (int i = 0; i < 4; ++i) {
    int node = n0 + nn + i;
    if (node < N) {
      float4 o = make_float4(acc[i][0], acc[i][1], acc[i][2], acc[i][3]);
      *(float4*)&Hout[node * 64 + c0] = o;
    }
  }
}

// Xout = sigmoid(A_norm . Hin + b). One wave per node, lane = feature.
// LAST: fuse the [64,1] W5 dot -> h5 (skip writing Xout entirely).
template <bool LAST>
__global__ __launch_bounds__(256) void k_agg64(const float* __restrict__ Hin,
                                               const float* __restrict__ dinv,
                                               const int* __restrict__ off,
                                               const int2* __restrict__ edat,
                                               const float* __restrict__ b,
                                               const float* __restrict__ W5,
                                               float* __restrict__ Xout,
                                               float* __restrict__ h5, int N) {
  int lane = threadIdx.x & 63;
  int wid = threadIdx.x >> 6;
  int node = blockIdx.x * 4 + wid;
  if (node >= N) return;
  float di = dinv[node];
  float acc = di * di * Hin[node * 64 + lane];  // self-loop
  int e = off[node], e1 = off[node + 1];
  for (; e + 1 < e1; e += 2) {
    int2 a = edat[e];
    int2 c = edat[e + 1];
    acc += __int_as_float(a.y) * Hin[a.x * 64 + lane];
    acc += __int_as_float(c.y) * Hin[c.x * 64 + lane];
  }
  if (e < e1) {
    int2 a = edat[e];
    acc += __int_as_float(a.y) * Hin[a.x * 64 + lane];
  }
  float xv = sigf(acc + b[lane]);
  if (LAST) {
    float v = xv * W5[lane];
#pragma unroll
    for (int d = 32; d; d >>= 1) v += __shfl_xor(v, d);
    if (lane == 0) h5[node] = v;
  } else {
    Xout[node * 64 + lane] = xv;
  }
}

// scalar aggregation + sigmoid + per-block partial sum
__global__ __launch_bounds__(256) void k_agg5(const float* __restrict__ h5,
                                              const float* __restrict__ dinv,
                                              const int* __restrict__ off,
                                              const int2* __restrict__ edat,
                                              const float* __restrict__ b5,
                                              float* __restrict__ partials, int N) {
  int n = blockIdx.x * 256 + threadIdx.x;
  float sig = 0.0f;
  if (n < N) {
    float di = dinv[n];
    float acc = di * di * h5[n];
    int e1 = off[n + 1];
    for (int e = off[n]; e < e1; ++e) {
      int2 a = edat[e];
      acc += __int_as_float(a.y) * h5[a.x];
    }
    sig = sigf(acc + b5[0]);
  }
#pragma unroll
  for (int d = 32; d; d >>= 1) sig += __shfl_xor(sig, d);
  __shared__ float ws[4];
  int lane = threadIdx.x & 63, wid = threadIdx.x >> 6;
  if (lane == 0) ws[wid] = sig;
  __syncthreads();
  if (threadIdx.x == 0) partials[blockIdx.x] = ws[0] + ws[1] + ws[2] + ws[3];
}

__global__ __launch_bounds__(512) void k_final(const float* __restrict__ partials,
                                               float* __restrict__ out, int nb,
                                               float invN) {
  float v = 0.0f;
  for (int i = threadIdx.x; i < nb; i += 512) v += partials[i];
#pragma unroll
  for (int d = 32; d; d >>= 1) v += __shfl_xor(v, d);
  __shared__ float ws[8];
  int lane = threadIdx.x & 63, wid = threadIdx.x >> 6;
  if (lane == 0) ws[wid] = v;
  __syncthreads();
  if (threadIdx.x == 0) {
    float s = 0.0f;
    for (int i = 0; i < 8; ++i) s += ws[i];
    out[0] = s * invN;
  }
}

extern "C" void kernel_launch(void* const* d_in, const int* in_sizes, int n_in,
                              void* d_out, int out_size, void* d_ws, size_t ws_size,
                              hipStream_t stream) {
  const float* vf = (const float*)d_in[0];
  const int* edges = (const int*)d_in[1];
  const float* w = (const float*)d_in[2];
  const float* W1 = (const float*)d_in[3];
  const float* b1 = (const float*)d_in[4];
  const float* W2 = (const float*)d_in[5];
  const float* b2 = (const float*)d_in[6];
  const float* W3 = (const float*)d_in[7];
  const float* b3 = (const float*)d_in[8];
  const float* W4 = (const float*)d_in[9];
  const float* b4 = (const float*)d_in[10];
  const float* W5 = (const float*)d_in[11];
  const float* b5 = (const float*)d_in[12];
  float* out = (float*)d_out;

  const int N = in_sizes[0] / 6;
  const int E = in_sizes[2];
  const int* row = edges;
  const int* col = edges + E;

  size_t o = 0;
  auto carve = [&](size_t bytes) -> void* {
    void* p = (char*)d_ws + o;
    o += (bytes + 255) & ~(size_t)255;
    return p;
  };
  float* X = (float*)carve((size_t)N * 64 * 4);
  float* H = (float*)carve((size_t)N * 64 * 4);  // also holds Sx [N,6]
  int2* edat = (int2*)carve((size_t)E * 8);      // {row, w|norm} interleaved
  float* dinv = (float*)carve((size_t)N * 4);
  int* off = (int*)carve((size_t)(N + 1) * 4);
  int* next = (int*)carve((size_t)N * 4);
  int* cnt = (int*)carve((size_t)N * 4);
  float* h5 = (float*)carve((size_t)N * 4);
  const int nb5 = (N + 255) / 256;
  float* partials = (float*)carve((size_t)nb5 * 4);

  hipMemsetAsync(cnt, 0, (size_t)N * 4, stream);

  const int eb = (E + 255) / 256;
  const int nb4 = (N + 3) / 4;
  k_hist<<<eb, 256, 0, stream>>>(col, cnt, E);
  k_scan<<<1, 1024, 0, stream>>>(cnt, off, next, N);
  k_scatter<<<eb, 256, 0, stream>>>(row, col, w, next, edat, E);
  k_deg<<<nb4, 256, 0, stream>>>(edat, off, dinv, N);
  k_norm<<<nb4, 256, 0, stream>>>(edat, off, dinv, N);

  // layer 1: aggregate features (D=6) then dense 6->64
  k_agg6<<<(N + 31) / 32, 256, 0, stream>>>(vf, dinv, off, edat, H, N);
  k_gemm1<<<(N + 63) / 64, 256, 0, stream>>>(H, W1, b1, X, N);

  // layers 2-3
  k_gemm64<<<(N + 63) / 64, 256, 0, stream>>>(X, W2, H, N);
  k_agg64<false><<<nb4, 256, 0, stream>>>(H, dinv, off, edat, b2, W5, X, h5, N);
  k_gemm64<<<(N + 63) / 64, 256, 0, stream>>>(X, W3, H, N);
  k_agg64<false><<<nb4, 256, 0, stream>>>(H, dinv, off, edat, b3, W5, X, h5, N);
  // layer 4 fused with W5 dot -> h5
  k_gemm64<<<(N + 63) / 64, 256, 0, stream>>>(X, W4, H, N);
  k_agg64<true><<<nb4, 256, 0, stream>>>(H, dinv, off, edat, b4, W5, X, h5, N);

  // layer 5: scalar aggregation + mean
  k_agg5<<<nb5, 256, 0, stream>>>(h5, dinv, off, edat, b5, partials, N);
  k_final<<<1, 512, 0, stream>>>(partials, out, nb5, 1.0f / (float)N);
}